// Round 3
// baseline (121.004 us; speedup 1.0000x reference)
//
#include <hip/hip_runtime.h>

#define NB   2
#define NCO  8
#define NCI  8
#define ND   8
#define NGH  16
#define NGW  16
#define NH   512
#define NW   512
#define NP   4          // pixels per thread
#define CHUNK (NP * 64) // 256 px per 1-wave block
#define NCHUNK 5        // ceil(35*35 / 256)

// One 64-thread (single-wave) block per (b, cell_y, cell_x, chunk); 4 px/thread.
// Cell grid values staged in LDS; epilogue reads them with wave-uniform
// ds_read_b128 (broadcast), amortized over 4 pixels.
__global__ __launch_bounds__(64, 4) void bslice_kernel(
    const float* __restrict__ grid,
    const float* __restrict__ guide,
    const float* __restrict__ inp,
    float* __restrict__ out)
{
    const int tid   = threadIdx.x;         // 0..63
    const int cx    = blockIdx.x;          // 0..14
    const int cy    = blockIdx.y;          // 0..14
    const int bz    = blockIdx.z;          // 0..9
    const int b     = bz & 1;
    const int chunk = bz >> 1;             // 0..4

    // pixel range of this cell: x with min(floor(x*15/511),14) == cx
    const int xs = (cx * (NW - 1) + (NGW - 2)) / (NGW - 1);
    const int xe = (cx == NGW - 2) ? NW : (((cx + 1) * (NW - 1) + (NGW - 2)) / (NGW - 1));
    const int ys = (cy * (NH - 1) + (NGH - 2)) / (NGH - 1);
    const int ye = (cy == NGH - 2) ? NH : (((cy + 1) * (NH - 1) + (NGH - 2)) / (NGH - 1));

    // LDS layout: [co][dy][dx][k][z]; bias (k=1) pre-scaled by 1/8.
    __shared__ float sg[NCO * 64];
    for (int i = tid; i < NCO * 64; i += 64) {
        int z  = i & 7;
        int k  = (i >> 3) & 1;
        int dx = (i >> 4) & 1;
        int dy = (i >> 5) & 1;
        int co = i >> 6;
        float v = grid[((((size_t)(b * NCO + co) * 2 + k) * ND + z) * NGH + (cy + dy)) * NGW + (cx + dx)];
        sg[i] = k ? v * 0.125f : v;
    }
    __syncthreads();

    const unsigned wcell = (unsigned)(xe - xs);
    const int npix = (int)wcell * (ye - ys);

    float S0[NP][8], S1[NP][8];
    float wgt[NP][4];
    int   poff[NP];
    bool  val[NP];

    const float step = (float)(NGH - 1) / (float)(NH - 1);   // 15/511
    const size_t inbase = (size_t)b * NCI * NH * NW;

    #pragma unroll
    for (int p = 0; p < NP; ++p) {
        int i = chunk * CHUNK + p * 64 + tid;
        val[p] = (i < npix);
        unsigned ii = (unsigned)(val[p] ? i : (npix - 1));
        unsigned q  = ii / wcell;
        int py = ys + (int)q;
        int px = xs + (int)(ii - q * wcell);

        float wy = (float)py * step - (float)cy;   // in (0,1]
        float wx = (float)px * step - (float)cx;
        wgt[p][0] = (1.f - wy) * (1.f - wx);
        wgt[p][1] = (1.f - wy) * wx;
        wgt[p][2] = wy * (1.f - wx);
        wgt[p][3] = wy * wx;

        poff[p] = py * NW + px;

        #pragma unroll
        for (int z = 0; z < 8; ++z) { S0[p][z] = 0.f; S1[p][z] = 0.f; }
    }

    // z-tent accumulation: S0[z] = sum_ci tent_z * inp, S1[z] = sum_ci tent_z.
    #pragma unroll
    for (int ci = 0; ci < NCI; ++ci) {
        const float* gp = guide + inbase + (size_t)ci * NH * NW;
        const float* vp = inp   + inbase + (size_t)ci * NH * NW;
        float g[NP], v[NP];
        #pragma unroll
        for (int p = 0; p < NP; ++p) {
            g[p] = gp[poff[p]];
            v[p] = vp[poff[p]];
        }
        #pragma unroll
        for (int p = 0; p < NP; ++p) {
            float zp = fminf(fmaxf(g[p] * 7.0f, 0.0f), 7.0f);
            #pragma unroll
            for (int z = 0; z < 8; ++z) {
                float a = fmaxf(0.0f, 1.0f - fabsf(zp - (float)z));
                S0[p][z] = fmaf(a, v[p], S0[p][z]);
                S1[p][z] += a;
            }
        }
    }

    const size_t obase = (size_t)b * NCO * NH * NW;

    #pragma unroll 1
    for (int co = 0; co < NCO; ++co) {
        float acc[NP];
        #pragma unroll
        for (int p = 0; p < NP; ++p) acc[p] = 0.f;

        #pragma unroll
        for (int c = 0; c < 4; ++c) {
            // 16 contiguous dwords for (co, corner c): [k=0 z0..7][k=1(bias/8) z0..7]
            const float4 w0 = *(const float4*)&sg[co * 64 + c * 16 + 0];
            const float4 w1 = *(const float4*)&sg[co * 64 + c * 16 + 4];
            const float4 b0 = *(const float4*)&sg[co * 64 + c * 16 + 8];
            const float4 b1 = *(const float4*)&sg[co * 64 + c * 16 + 12];
            #pragma unroll
            for (int p = 0; p < NP; ++p) {
                float t;
                t = S0[p][0] * w0.x;
                t = fmaf(S0[p][1], w0.y, t);
                t = fmaf(S0[p][2], w0.z, t);
                t = fmaf(S0[p][3], w0.w, t);
                t = fmaf(S0[p][4], w1.x, t);
                t = fmaf(S0[p][5], w1.y, t);
                t = fmaf(S0[p][6], w1.z, t);
                t = fmaf(S0[p][7], w1.w, t);
                t = fmaf(S1[p][0], b0.x, t);
                t = fmaf(S1[p][1], b0.y, t);
                t = fmaf(S1[p][2], b0.z, t);
                t = fmaf(S1[p][3], b0.w, t);
                t = fmaf(S1[p][4], b1.x, t);
                t = fmaf(S1[p][5], b1.y, t);
                t = fmaf(S1[p][6], b1.z, t);
                t = fmaf(S1[p][7], b1.w, t);
                acc[p] = fmaf(wgt[p][c], t, acc[p]);
            }
        }
        #pragma unroll
        for (int p = 0; p < NP; ++p)
            if (val[p])
                out[obase + (size_t)co * NH * NW + poff[p]] = acc[p];
    }
}

extern "C" void kernel_launch(void* const* d_in, const int* in_sizes, int n_in,
                              void* d_out, int out_size, void* d_ws, size_t ws_size,
                              hipStream_t stream) {
    const float* grid  = (const float*)d_in[0];
    const float* guide = (const float*)d_in[1];
    const float* inp   = (const float*)d_in[2];
    float* out = (float*)d_out;

    dim3 g(NGW - 1, NGH - 1, NB * NCHUNK);   // (15, 15, 10) = 2250 one-wave blocks
    bslice_kernel<<<g, 64, 0, stream>>>(grid, guide, inp, out);
}